// Round 5
// baseline (51.730 us; speedup 1.0000x reference)
//
#include <hip/hip_runtime.h>

constexpr int B_ = 16;
constexpr int N_ = 500;
constexpr int NC = 10;
constexpr int FM_ = 360;
constexpr int RMAXC = 12;
constexpr long HM_ELEMS = (long)B_ * NC * FM_ * FM_;      // 20,736,000
constexpr long ANNO_OFF = HM_ELEMS;                        // +16*500*8 = 64,000
constexpr long IND_OFF  = ANNO_OFF + (long)B_ * N_ * 8;    // 20,800,000
constexpr long MASK_OFF = IND_OFF + (long)B_ * N_;         // 20,808,000

constexpr int ROWS = 8;                       // rows per gather stripe
constexpr int STRIPES = FM_ / ROWS;           // 45
constexpr int GATHER_BLKS = B_ * NC * STRIPES;// 7200
constexpr int PREP_BLKS = 32;                 // 2 per batch

struct ObjParams {
    float cx_f, cy_f, sigma;
    int cx, cy, radius;
    bool valid;
};

// Replicates reference float32 op order exactly.
__device__ inline ObjParams compute_params(const float* bx) {
    float x = bx[0], y = bx[1];
    float w = bx[3], l = bx[4];
    ObjParams o;
    float wp = w / 0.075f / 4.0f;
    float lp = l / 0.075f / 4.0f;
    o.cx_f = (x + 54.0f) / 0.075f / 4.0f;   // (x - PCR0), PCR0 = -54.0
    o.cy_f = (y + 54.0f) / 0.075f / 4.0f;
    o.cx = (int)o.cx_f;                      // trunc == .astype(int32)
    o.cy = (int)o.cy_f;
    o.valid = (wp > 0.0f) && (lp > 0.0f) &&
              (o.cx >= 0) && (o.cx < FM_) && (o.cy >= 0) && (o.cy < FM_);
    // gaussian_radius(height=lp, width=wp, min_overlap=0.1)
    float height = lp, width = wp;
    float b1 = height + width;
    float c1 = width * height * 0.9f / 1.1f;
    float r1 = (b1 + sqrtf(b1 * b1 - 4.0f * c1)) / 2.0f;
    float b2 = 2.0f * (height + width);
    float c2 = 0.9f * width * height;
    float r2 = (b2 + sqrtf(b2 * b2 - 16.0f * c2)) / 2.0f;
    float b3 = -0.2f * (height + width);
    float c3 = -0.9f * width * height;
    float r3 = (b3 + sqrtf(b3 * b3 - 1.6f * c3)) / 2.0f;
    float r = fminf(fminf(r1, r2), r3);
    o.radius = max(2, (int)floorf(r));
    o.sigma = (2.0f * (float)o.radius + 1.0f) / 6.0f;
    return o;
}

// One kernel. Blocks [0, GATHER_BLKS): each owns one (batch, class, 8-row
// stripe) of the heatmap — gathers max-gaussian per pixel and writes each
// output float exactly once (no zero pass, no atomics). Blocks
// [GATHER_BLKS, +PREP_BLKS): stable rank + anno/ind/mask (disjoint region).
__global__ __launch_bounds__(256) void fused_gather_kernel(
        const float* __restrict__ boxes, const int* __restrict__ labels,
        float* __restrict__ out) {
    int blk = blockIdx.x;
    int tid = threadIdx.x;

    if (blk < GATHER_BLKS) {
        int b = blk / (NC * STRIPES);
        int rem = blk - b * (NC * STRIPES);
        int c = rem / STRIPES;
        int stripe = rem - c * STRIPES;
        int y0 = stripe * ROWS;

        __shared__ int s_cnt;
        __shared__ int s_cx[N_], s_cy[N_], s_re[N_];
        __shared__ float s_den[N_];
        if (tid == 0) s_cnt = 0;
        __syncthreads();

        // Filter: objects of this batch+class whose window intersects stripe.
        for (int k = tid; k < N_; k += 256) {
            if (labels[b * N_ + k] - 1 != c) continue;
            const float* bx = boxes + (long)(b * N_ + k) * 9;
            ObjParams o = compute_params(bx);
            if (!o.valid) continue;
            int reff = min(o.radius, RMAXC);
            if (o.cy + reff < y0 || o.cy - reff > y0 + ROWS - 1) continue;
            int p = atomicAdd(&s_cnt, 1);
            s_cx[p] = o.cx;
            s_cy[p] = o.cy;
            s_re[p] = reff;
            s_den[p] = 2.0f * (o.sigma * o.sigma);  // 2*sigma**2, exact op order
        }
        __syncthreads();
        int n = s_cnt;

        float4* base4 = (float4*)(out + (((long)(b * NC + c)) * FM_ + y0) * FM_);
        constexpr int NF4 = ROWS * FM_ / 4;           // 720 float4 per stripe
        for (int k = tid; k < NF4; k += 256) {
            int row = k / 90;                          // 90 float4 per row
            int y = y0 + row;
            int x0 = (k - row * 90) * 4;
            float4 acc = {0.f, 0.f, 0.f, 0.f};
            for (int j = 0; j < n; ++j) {
                int dy = y - s_cy[j];
                int re = s_re[j];
                if (dy > re || dy < -re) continue;
                int cxj = s_cx[j];
                float den = s_den[j];
                float fdy2 = (float)(dy * dy);
                #pragma unroll
                for (int i = 0; i < 4; ++i) {
                    int dx = x0 + i - cxj;
                    if (dx > re || dx < -re) continue;
                    float d2 = (float)(dx * dx) + fdy2;   // exact: ints <= 288
                    float g = expf(-d2 / den);
                    float* a = (float*)&acc + i;
                    *a = fmaxf(*a, g);
                }
            }
            base4[k] = acc;
        }
    } else {
        // ---- prep: stable rank by label + anno/ind/mask ----
        int blk2 = blk - GATHER_BLKS;
        int b = blk2 >> 1;
        int half = blk2 & 1;
        __shared__ int lab[N_];
        for (int k = tid; k < N_; k += 256) lab[k] = labels[b * N_ + k];
        __syncthreads();
        int i = half * 250 + tid;
        if (tid < 250) {
            int c = lab[i];
            int rank = 0;
            #pragma unroll 8
            for (int j = 0; j < N_; ++j) {
                int lj = lab[j];
                rank += (lj < c) | ((lj == c) & (j < i));
            }
            const float* bx = boxes + (long)(b * N_ + i) * 9;
            ObjParams o = compute_params(bx);
            float* anno = out + ANNO_OFF + (long)(b * N_ + rank) * 8;
            if (o.valid) {
                float zz = bx[2], w = bx[3], l = bx[4], h = bx[5], rot = bx[8];
                float4 a0 = {o.cx_f - (float)o.cx, o.cy_f - (float)o.cy, zz, logf(w)};
                float4 a1 = {logf(l), logf(h), sinf(rot), cosf(rot)};
                *(float4*)anno = a0;
                *(float4*)(anno + 4) = a1;
                out[IND_OFF + b * N_ + rank]  = (float)(o.cy * FM_ + o.cx);
                out[MASK_OFF + b * N_ + rank] = 1.0f;
            } else {
                float4 z = {0.f, 0.f, 0.f, 0.f};
                *(float4*)anno = z;
                *(float4*)(anno + 4) = z;
                out[IND_OFF + b * N_ + rank]  = 0.0f;
                out[MASK_OFF + b * N_ + rank] = 0.0f;
            }
        }
    }
}

extern "C" void kernel_launch(void* const* d_in, const int* in_sizes, int n_in,
                              void* d_out, int out_size, void* d_ws, size_t ws_size,
                              hipStream_t stream) {
    const float* boxes = (const float*)d_in[0];
    const int* labels  = (const int*)d_in[1];
    float* out = (float*)d_out;

    fused_gather_kernel<<<GATHER_BLKS + PREP_BLKS, 256, 0, stream>>>(
        boxes, labels, out);
}

// Round 6
// 44.411 us; speedup vs baseline: 1.1648x; 1.1648x over previous
//
#include <hip/hip_runtime.h>

constexpr int B_ = 16;
constexpr int N_ = 500;
constexpr int NC = 10;
constexpr int FM_ = 360;
constexpr int RMAXC = 12;
constexpr long HM_ELEMS = (long)B_ * NC * FM_ * FM_;      // 20,736,000
constexpr long ANNO_OFF = HM_ELEMS;                        // +16*500*8 = 64,000
constexpr long IND_OFF  = ANNO_OFF + (long)B_ * N_ * 8;    // 20,800,000
constexpr long MASK_OFF = IND_OFF + (long)B_ * N_;         // 20,808,000

constexpr int BAND = 36;                      // rows per gather block
constexpr int NBANDS = FM_ / BAND;            // 10
constexpr int GATHER_BLKS = B_ * NC * NBANDS; // 1600
constexpr int PREP_BLKS = 32;                 // 2 per batch

struct ObjParams {
    float cx_f, cy_f, sigma;
    int cx, cy, radius;
    bool valid;
};

// Replicates reference float32 op order exactly (divides stay true divides:
// they feed trunc/floor discretization).
__device__ inline ObjParams compute_params(const float* bx) {
    float x = bx[0], y = bx[1];
    float w = bx[3], l = bx[4];
    ObjParams o;
    float wp = w / 0.075f / 4.0f;
    float lp = l / 0.075f / 4.0f;
    o.cx_f = (x + 54.0f) / 0.075f / 4.0f;   // (x - PCR0), PCR0 = -54.0
    o.cy_f = (y + 54.0f) / 0.075f / 4.0f;
    o.cx = (int)o.cx_f;                      // trunc == .astype(int32)
    o.cy = (int)o.cy_f;
    o.valid = (wp > 0.0f) && (lp > 0.0f) &&
              (o.cx >= 0) && (o.cx < FM_) && (o.cy >= 0) && (o.cy < FM_);
    // gaussian_radius(height=lp, width=wp, min_overlap=0.1)
    float height = lp, width = wp;
    float b1 = height + width;
    float c1 = width * height * 0.9f / 1.1f;
    float r1 = (b1 + sqrtf(b1 * b1 - 4.0f * c1)) / 2.0f;
    float b2 = 2.0f * (height + width);
    float c2 = 0.9f * width * height;
    float r2 = (b2 + sqrtf(b2 * b2 - 16.0f * c2)) / 2.0f;
    float b3 = -0.2f * (height + width);
    float c3 = -0.9f * width * height;
    float r3 = (b3 + sqrtf(b3 * b3 - 1.6f * c3)) / 2.0f;
    float r = fminf(fminf(r1, r2), r3);
    o.radius = max(2, (int)floorf(r));
    o.sigma = (2.0f * (float)o.radius + 1.0f) / 6.0f;
    return o;
}

// One kernel. Blocks [0, GATHER_BLKS): each owns one (batch, class, 36-row
// band) — gathers max-gaussian per pixel, writes each output float exactly
// once (no zero pass, no atomics). Blocks [GATHER_BLKS, +PREP_BLKS):
// stable rank + anno/ind/mask (disjoint output region, no sync needed).
__global__ __launch_bounds__(256) void fused_gather_kernel(
        const float* __restrict__ boxes, const int* __restrict__ labels,
        float* __restrict__ out) {
    int blk = blockIdx.x;
    int tid = threadIdx.x;

    if (blk < GATHER_BLKS) {
        int b = blk / (NC * NBANDS);
        int rem = blk - b * (NC * NBANDS);
        int c = rem / NBANDS;
        int y0 = (rem - c * NBANDS) * BAND;

        __shared__ int s_cnt;
        __shared__ int s_cx[N_], s_cy[N_], s_re[N_];
        __shared__ float s_inv[N_];
        if (tid == 0) s_cnt = 0;
        __syncthreads();

        // Objects of this batch+class whose window intersects the band.
        for (int k = tid; k < N_; k += 256) {
            if (labels[b * N_ + k] - 1 != c) continue;
            const float* bx = boxes + (long)(b * N_ + k) * 9;
            ObjParams o = compute_params(bx);
            if (!o.valid) continue;
            int reff = min(o.radius, RMAXC);
            if (o.cy + reff < y0 || o.cy - reff > y0 + BAND - 1) continue;
            int p = atomicAdd(&s_cnt, 1);
            s_cx[p] = o.cx;
            s_cy[p] = o.cy;
            s_re[p] = reff;
            // exp arg uses reciprocal-mul: |delta g| <= e^-1 * 2^-24 ~ 2e-9.
            s_inv[p] = 1.0f / (2.0f * (o.sigma * o.sigma));
        }
        __syncthreads();
        int n = s_cnt;

        float4* base4 = (float4*)(out + (((long)(b * NC + c)) * FM_ + y0) * FM_);
        constexpr int NF4 = BAND * FM_ / 4;           // 3240 float4 per band
        for (int k = tid; k < NF4; k += 256) {
            int row = k / 90;                          // 90 float4 per row
            int y = y0 + row;
            int x0 = (k - row * 90) * 4;
            float4 acc = {0.f, 0.f, 0.f, 0.f};
            for (int j = 0; j < n; ++j) {
                int dy = y - s_cy[j];
                int re = s_re[j];
                if (dy > re || dy < -re) continue;
                int dxb = x0 - s_cx[j];
                if (dxb > re || dxb + 3 < -re) continue;
                float inv = s_inv[j];
                float fdy2 = (float)(dy * dy);
                #pragma unroll
                for (int i = 0; i < 4; ++i) {
                    int dx = dxb + i;
                    if (dx > re || dx < -re) continue;
                    float g = expf(-((float)(dx * dx) + fdy2) * inv);
                    float* a = (float*)&acc + i;
                    *a = fmaxf(*a, g);
                }
            }
            base4[k] = acc;
        }
    } else {
        // ---- prep: stable rank by label + anno/ind/mask ----
        int blk2 = blk - GATHER_BLKS;
        int b = blk2 >> 1;
        int half = blk2 & 1;
        __shared__ int lab[N_];
        for (int k = tid; k < N_; k += 256) lab[k] = labels[b * N_ + k];
        __syncthreads();
        int i = half * 250 + tid;
        if (tid < 250) {
            int c = lab[i];
            int rank = 0;
            #pragma unroll 8
            for (int j = 0; j < N_; ++j) {
                int lj = lab[j];
                rank += (lj < c) | ((lj == c) & (j < i));
            }
            const float* bx = boxes + (long)(b * N_ + i) * 9;
            ObjParams o = compute_params(bx);
            float* anno = out + ANNO_OFF + (long)(b * N_ + rank) * 8;
            if (o.valid) {
                float zz = bx[2], w = bx[3], l = bx[4], h = bx[5], rot = bx[8];
                float4 a0 = {o.cx_f - (float)o.cx, o.cy_f - (float)o.cy, zz, logf(w)};
                float4 a1 = {logf(l), logf(h), sinf(rot), cosf(rot)};
                *(float4*)anno = a0;
                *(float4*)(anno + 4) = a1;
                out[IND_OFF + b * N_ + rank]  = (float)(o.cy * FM_ + o.cx);
                out[MASK_OFF + b * N_ + rank] = 1.0f;
            } else {
                float4 z = {0.f, 0.f, 0.f, 0.f};
                *(float4*)anno = z;
                *(float4*)(anno + 4) = z;
                out[IND_OFF + b * N_ + rank]  = 0.0f;
                out[MASK_OFF + b * N_ + rank] = 0.0f;
            }
        }
    }
}

extern "C" void kernel_launch(void* const* d_in, const int* in_sizes, int n_in,
                              void* d_out, int out_size, void* d_ws, size_t ws_size,
                              hipStream_t stream) {
    const float* boxes = (const float*)d_in[0];
    const int* labels  = (const int*)d_in[1];
    float* out = (float*)d_out;

    fused_gather_kernel<<<GATHER_BLKS + PREP_BLKS, 256, 0, stream>>>(
        boxes, labels, out);
}